// Round 1
// baseline (351.384 us; speedup 1.0000x reference)
//
#include <hip/hip_runtime.h>

// Problem constants (reference file)
#define D 1024          // X_DIM
#define N_ITERS 21      // 20 CCP steps + 1 final get_f_ders score

// out_i = s where s = s0_i; repeat 21x: z=s+1; nab=0.5*z*rsqrt(z^2+1); s = s0_i + 0.5*nab*ww
// with s0_i = X[i,:].w + b, ww = ||w||^2.  (TRAIN_SLOPE=1, SCALE=1 -> inv=0.5)

__global__ __launch_bounds__(256) void ccp_matvec_kernel(
    const float* __restrict__ X,
    const float* __restrict__ w,
    const float* __restrict__ b,
    float* __restrict__ out,
    int batch)
{
    const int wave = threadIdx.x >> 6;             // 4 waves/block
    const int lane = threadIdx.x & 63;
    const int row  = blockIdx.x * 4 + wave;
    if (row >= batch) return;

    const float4* __restrict__ Xv = (const float4*)(X + (size_t)row * D);
    const float4* __restrict__ Wv = (const float4*)w;

    float dot = 0.f, wsq = 0.f;
#pragma unroll
    for (int k = 0; k < D / 4 / 64; ++k) {         // 4 float4 loads per lane
        float4 xv = Xv[lane + k * 64];
        float4 wv = Wv[lane + k * 64];
        dot = fmaf(xv.x, wv.x, dot);
        dot = fmaf(xv.y, wv.y, dot);
        dot = fmaf(xv.z, wv.z, dot);
        dot = fmaf(xv.w, wv.w, dot);
        wsq = fmaf(wv.x, wv.x, wsq);
        wsq = fmaf(wv.y, wv.y, wsq);
        wsq = fmaf(wv.z, wv.z, wsq);
        wsq = fmaf(wv.w, wv.w, wsq);
    }

    // 64-lane reduction (wave = 64 on CDNA)
#pragma unroll
    for (int off = 32; off; off >>= 1) {
        dot += __shfl_down(dot, off, 64);
        wsq += __shfl_down(wsq, off, 64);
    }

    if (lane == 0) {
        const float ww = wsq;
        const float s0 = dot + b[0];
        float s = s0;
#pragma unroll
        for (int t = 0; t < N_ITERS; ++t) {
            float z   = s + 1.0f;                       // slope = 1
            float nab = 0.5f * z * rsqrtf(fmaf(z, z, 1.0f));
            s = fmaf(0.5f * ww, nab, s0);               // inv = 1/(2*scale) = 0.5
        }
        out[row] = s;
    }
}

extern "C" void kernel_launch(void* const* d_in, const int* in_sizes, int n_in,
                              void* d_out, int out_size, void* d_ws, size_t ws_size,
                              hipStream_t stream) {
    const float* X = (const float*)d_in[0];
    const float* w = (const float*)d_in[1];
    const float* b = (const float*)d_in[2];
    float* out = (float*)d_out;

    const int batch = in_sizes[0] / D;                  // 65536
    const int rows_per_block = 4;                       // 4 waves of 64
    dim3 grid((batch + rows_per_block - 1) / rows_per_block);
    dim3 block(256);
    ccp_matvec_kernel<<<grid, block, 0, stream>>>(X, w, b, out, batch);
}

// Round 3
// 329.828 us; speedup vs baseline: 1.0654x; 1.0654x over previous
//
#include <hip/hip_runtime.h>

// Problem constants (reference file)
#define D 1024          // X_DIM
#define N_ITERS 21      // 20 CCP steps + 1 final get_f_ders score

// Algebraic collapse of the CCP loop: every iterate is x_t = X + c_t*w, so
// s_t = x_t.w + b = s0 + c_t*||w||^2 with c_t = 0.5*nabla_f(s_{t-1}).
//   s0 = X.w + b,  ww = ||w||^2
//   repeat 21x: z = s+1; nab = 0.5*z*rsqrt(z^2+1); s = s0 + 0.5*nab*ww
// Output = s (the 21st update IS X_opt.w + b).  TRAIN_SLOPE=1, SCALE=1.

typedef float v4f __attribute__((ext_vector_type(4)));  // native vector: valid
                                                        // for __builtin_nontemporal_load

__global__ __launch_bounds__(256) void ccp_matvec_kernel(
    const float* __restrict__ X,
    const float* __restrict__ w,
    const float* __restrict__ b,
    float* __restrict__ out,
    int batch)
{
    const int wave = threadIdx.x >> 6;             // 4 waves/block
    const int lane = threadIdx.x & 63;
    const int row0 = (blockIdx.x * 4 + wave) * 2;  // 2 rows per wave
    if (row0 >= batch) return;

    const v4f* __restrict__ Xa = (const v4f*)(X + (size_t)row0 * D);
    const v4f* __restrict__ Xb = Xa + D / 4;       // row0+1
    const v4f* __restrict__ Wv = (const v4f*)w;

    // Issue all loads up front: 4 w (L1-resident) + 8 X (streaming, nt).
    v4f wv[4], xa[4], xb[4];
#pragma unroll
    for (int k = 0; k < 4; ++k) wv[k] = Wv[lane + k * 64];
#pragma unroll
    for (int k = 0; k < 4; ++k) xa[k] = __builtin_nontemporal_load(&Xa[lane + k * 64]);
#pragma unroll
    for (int k = 0; k < 4; ++k) xb[k] = __builtin_nontemporal_load(&Xb[lane + k * 64]);

    float dota = 0.f, dotb = 0.f, wsq = 0.f;
#pragma unroll
    for (int k = 0; k < 4; ++k) {
#pragma unroll
        for (int j = 0; j < 4; ++j) {
            dota = fmaf(xa[k][j], wv[k][j], dota);
            dotb = fmaf(xb[k][j], wv[k][j], dotb);
            wsq  = fmaf(wv[k][j], wv[k][j], wsq);
        }
    }

    // Butterfly reduction: every lane ends with the full sums.
#pragma unroll
    for (int off = 32; off; off >>= 1) {
        dota += __shfl_xor(dota, off, 64);
        dotb += __shfl_xor(dotb, off, 64);
        wsq  += __shfl_xor(wsq,  off, 64);
    }

    // Lanes 0 and 1 each run the 21-step recurrence for one row (same code
    // path -> no divergence; per-row tail issue cost halved vs 1 row/wave).
    if (lane < 2) {
        const float ww = wsq;
        const float s0 = (lane == 0 ? dota : dotb) + b[0];
        float s = s0;
#pragma unroll
        for (int t = 0; t < N_ITERS; ++t) {
            float z   = s + 1.0f;                       // slope = 1
            float nab = 0.5f * z * rsqrtf(fmaf(z, z, 1.0f));
            s = fmaf(0.5f * ww, nab, s0);               // inv = 1/(2*scale) = 0.5
        }
        out[row0 + lane] = s;
    }
}

extern "C" void kernel_launch(void* const* d_in, const int* in_sizes, int n_in,
                              void* d_out, int out_size, void* d_ws, size_t ws_size,
                              hipStream_t stream) {
    const float* X = (const float*)d_in[0];
    const float* w = (const float*)d_in[1];
    const float* b = (const float*)d_in[2];
    float* out = (float*)d_out;

    const int batch = in_sizes[0] / D;                  // 65536
    const int rows_per_block = 8;                       // 4 waves x 2 rows
    dim3 grid((batch + rows_per_block - 1) / rows_per_block);
    dim3 block(256);
    ccp_matvec_kernel<<<grid, block, 0, stream>>>(X, w, b, out, batch);
}